// Round 1
// baseline (1705.832 us; speedup 1.0000x reference)
//
#include <hip/hip_runtime.h>
#include <hip/hip_bf16.h>

#define H 64

// ---------------------------------------------------------------- count
__global__ void count_kernel(const int* __restrict__ eidx, int* __restrict__ cnt_t,
                             int* __restrict__ cnt_s, int E) {
    int stride = gridDim.x * blockDim.x;
    for (int e = blockIdx.x * blockDim.x + threadIdx.x; e < E; e += stride) {
        int s = eidx[e];
        int d = eidx[E + e];
        atomicAdd(&cnt_s[s], 1);
        atomicAdd(&cnt_t[d], 1);
    }
}

// ---------------------------------------------------------------- scan (3-phase)
// grid (nblk, 2): arr 0 = targets, arr 1 = sources. 1024 elems / block.
__global__ void scan_local(const int* __restrict__ cnt, int* __restrict__ off,
                           int* __restrict__ partials, int n) {
    int arr = blockIdx.y;
    const int* c = cnt + (size_t)arr * n;
    int* o = off + (size_t)arr * n;
    int base = blockIdx.x * 1024;
    int tid = threadIdx.x;
    int v[4];
    int t = 0;
#pragma unroll
    for (int q = 0; q < 4; q++) {
        int i = base + tid * 4 + q;
        v[q] = (i < n) ? c[i] : 0;
        t += v[q];
    }
    __shared__ int s[256];
    s[tid] = t;
    __syncthreads();
    for (int ofs = 1; ofs < 256; ofs <<= 1) {
        int add = (tid >= ofs) ? s[tid - ofs] : 0;
        __syncthreads();
        s[tid] += add;
        __syncthreads();
    }
    int excl = s[tid] - t;   // exclusive prefix of this thread within block
#pragma unroll
    for (int q = 0; q < 4; q++) {
        int i = base + tid * 4 + q;
        if (i < n) o[i] = excl;
        excl += v[q];
    }
    if (tid == 0) partials[arr * 128 + blockIdx.x] = s[255];
}

__global__ void scan_partials(int* __restrict__ partials, int nblk) {
    int t = threadIdx.x;
    if (t < 2) {
        int run = 0;
        for (int b = 0; b < nblk; b++) {
            int p = partials[t * 128 + b];
            partials[t * 128 + b] = run;
            run += p;
        }
    }
}

__global__ void scan_add(int* __restrict__ off, const int* __restrict__ partials, int n) {
    int arr = blockIdx.y;
    int* o = off + (size_t)arr * n;
    int add = partials[arr * 128 + blockIdx.x];
    int base = blockIdx.x * 1024;
    int tid = threadIdx.x;
#pragma unroll
    for (int q = 0; q < 4; q++) {
        int i = base + tid * 4 + q;
        if (i < n) o[i] += add;
    }
}

// ---------------------------------------------------------------- fill CSR
__global__ void fill_kernel(const int* __restrict__ eidx,
                            const int* __restrict__ off_t, const int* __restrict__ off_s,
                            int* __restrict__ cur_t, int* __restrict__ cur_s,
                            int* __restrict__ csr_t, int* __restrict__ csr_s, int E) {
    int stride = gridDim.x * blockDim.x;
    for (int e = blockIdx.x * blockDim.x + threadIdx.x; e < E; e += stride) {
        int s = eidx[e];
        int d = eidx[E + e];
        int pt = atomicAdd(&cur_t[d], 1);
        csr_t[off_t[d] + pt] = s;
        int ps = atomicAdd(&cur_s[s], 1);
        csr_s[off_s[s] + ps] = d;
    }
}

// ---------------------------------------------------------------- mean aggregation
// one wave per destination node; lane j owns feature j
__global__ void agg_mean(const float* __restrict__ x, const int* __restrict__ csr,
                         const int* __restrict__ off, const int* __restrict__ cnt,
                         float* __restrict__ out, int n) {
    int w = threadIdx.x >> 6, j = threadIdx.x & 63;
    int node = blockIdx.x * 4 + w;
    if (node >= n) return;
    int o = off[node], c = cnt[node];
    float acc = 0.f;
    for (int k = 0; k < c; k++) {
        int idx = csr[o + k];
        acc += x[(size_t)idx * H + j];
    }
    out[(size_t)node * H + j] = acc / fmaxf((float)c, 1.f);
}

// ---------------------------------------------------------------- fused linear
// out[n][j] = act( sum_k agg[n][k]*Wl[k][j] + x[n][k]*Wr[k][j] + b[j] )
// thread j holds column j of Wl and Wr in registers; 64 nodes per block.
template <bool RELU>
__global__ __launch_bounds__(256, 2) void fused_lin(const float* __restrict__ agg,
                                                    const float* __restrict__ xd,
                                                    const float* __restrict__ Wl,
                                                    const float* __restrict__ Wr,
                                                    const float* __restrict__ b,
                                                    float* __restrict__ out, int n) {
    int tid = threadIdx.x;
    int w = tid >> 6, j = tid & 63;
    float wl[H], wr[H];
#pragma unroll
    for (int k = 0; k < H; k++) {
        wl[k] = Wl[k * H + j];
        wr[k] = Wr[k * H + j];
    }
    float bj = b[j];
    int base = blockIdx.x * 64;
    for (int it = 0; it < 16; ++it) {
        int node = base + it * 4 + w;
        if (node < n) {
            const float4* av = (const float4*)(agg + (size_t)node * H);
            const float4* xv = (const float4*)(xd + (size_t)node * H);
            float acc = bj;
#pragma unroll
            for (int k4 = 0; k4 < 16; k4++) {
                float4 a = av[k4];
                float4 xx = xv[k4];
                acc += a.x * wl[4 * k4 + 0] + a.y * wl[4 * k4 + 1] +
                       a.z * wl[4 * k4 + 2] + a.w * wl[4 * k4 + 3];
                acc += xx.x * wr[4 * k4 + 0] + xx.y * wr[4 * k4 + 1] +
                       xx.z * wr[4 * k4 + 2] + xx.w * wr[4 * k4 + 3];
            }
            out[(size_t)node * H + j] = RELU ? fmaxf(acc, 0.f) : acc;
        }
    }
}

// ---------------------------------------------------------------- link scores
__global__ void dot_kernel(const float* __restrict__ os, const float* __restrict__ ot,
                           const int* __restrict__ ell, float* __restrict__ out, int ne) {
    int w = threadIdx.x >> 6, j = threadIdx.x & 63;
    int l = blockIdx.x * 4 + w;
    if (l >= ne) return;
    int s = ell[l];
    int d = ell[ne + l];
    float p = os[(size_t)s * H + j] * ot[(size_t)d * H + j];
#pragma unroll
    for (int ofs = 32; ofs > 0; ofs >>= 1) p += __shfl_xor(p, ofs, 64);
    if (j == 0) out[l] = p;
}

// ----------------------------------------------------------------
static inline size_t alignup(size_t x) { return (x + 255) & ~(size_t)255; }

extern "C" void kernel_launch(void* const* d_in, const int* in_sizes, int n_in,
                              void* d_out, int out_size, void* d_ws, size_t ws_size,
                              hipStream_t stream) {
    const float* src_emb = (const float*)d_in[0];
    const float* tgt_emb = (const float*)d_in[1];
    const float* Wl_st1 = (const float*)d_in[2];
    const float* Wr_st1 = (const float*)d_in[3];
    const float* b_st1 = (const float*)d_in[4];
    const float* Wl_ts1 = (const float*)d_in[5];
    const float* Wr_ts1 = (const float*)d_in[6];
    const float* b_ts1 = (const float*)d_in[7];
    const float* Wl_st2 = (const float*)d_in[8];
    const float* Wr_st2 = (const float*)d_in[9];
    const float* b_st2 = (const float*)d_in[10];
    const float* Wl_ts2 = (const float*)d_in[11];
    const float* Wr_ts2 = (const float*)d_in[12];
    const float* b_ts2 = (const float*)d_in[13];
    const int* eidx = (const int*)d_in[14];
    const int* ell = (const int*)d_in[15];

    const int NS = in_sizes[0] / H;     // 100000
    const int NT = in_sizes[1] / H;     // 100000
    const int E = in_sizes[14] / 2;     // 2000000
    const int EL = in_sizes[15] / 2;    // 500000
    const int NN = NT;                  // NS == NT here

    char* ws = (char*)d_ws;
    size_t o_cnt = 0;                               // cnt_t, cnt_s : 2*NN ints
    size_t o_cur = alignup(o_cnt + (size_t)2 * NN * 4);  // cur_t, cur_s
    size_t o_off = alignup(o_cur + (size_t)2 * NN * 4);  // off_t, off_s
    size_t o_par = alignup(o_off + (size_t)2 * NN * 4);  // partials 2*128
    size_t o_csrt = alignup(o_par + 1024);
    size_t o_csrs = alignup(o_csrt + (size_t)E * 4);
    size_t o_aggA = alignup(o_csrs + (size_t)E * 4);
    size_t o_aggB = alignup(o_aggA + (size_t)NN * H * 4);
    size_t o_ht = alignup(o_aggB + (size_t)NN * H * 4);
    size_t o_hs = alignup(o_ht + (size_t)NN * H * 4);

    int* cnt = (int*)(ws + o_cnt);
    int* cnt_t = cnt;
    int* cnt_s = cnt + NN;
    int* cur_t = (int*)(ws + o_cur);
    int* cur_s = cur_t + NN;
    int* off = (int*)(ws + o_off);
    int* off_t = off;
    int* off_s = off + NN;
    int* par = (int*)(ws + o_par);
    int* csr_t = (int*)(ws + o_csrt);
    int* csr_s = (int*)(ws + o_csrs);
    float* aggA = (float*)(ws + o_aggA);
    float* aggB = (float*)(ws + o_aggB);
    float* h_t = (float*)(ws + o_ht);
    float* h_s = (float*)(ws + o_hs);
    float* out = (float*)d_out;

    // zero counters + cursors (contiguous region)
    hipMemsetAsync(ws + o_cnt, 0, o_off - o_cnt, stream);

    count_kernel<<<2048, 256, 0, stream>>>(eidx, cnt_t, cnt_s, E);

    int nblk = (NN + 1023) / 1024;
    scan_local<<<dim3(nblk, 2), 256, 0, stream>>>(cnt, off, par, NN);
    scan_partials<<<1, 64, 0, stream>>>(par, nblk);
    scan_add<<<dim3(nblk, 2), 256, 0, stream>>>(off, par, NN);

    fill_kernel<<<2048, 256, 0, stream>>>(eidx, off_t, off_s, cur_t, cur_s, csr_t, csr_s, E);

    int gagg = (NN + 3) / 4;
    int glin = (NN + 63) / 64;

    // layer 1
    agg_mean<<<gagg, 256, 0, stream>>>(src_emb, csr_t, off_t, cnt_t, aggA, NT);
    agg_mean<<<gagg, 256, 0, stream>>>(tgt_emb, csr_s, off_s, cnt_s, aggB, NS);
    fused_lin<true><<<glin, 256, 0, stream>>>(aggA, tgt_emb, Wl_st1, Wr_st1, b_st1, h_t, NT);
    fused_lin<true><<<glin, 256, 0, stream>>>(aggB, src_emb, Wl_ts1, Wr_ts1, b_ts1, h_s, NS);

    // layer 2
    agg_mean<<<gagg, 256, 0, stream>>>(h_s, csr_t, off_t, cnt_t, aggA, NT);
    agg_mean<<<gagg, 256, 0, stream>>>(h_t, csr_s, off_s, cnt_s, aggB, NS);
    fused_lin<false><<<glin, 256, 0, stream>>>(aggA, h_t, Wl_st2, Wr_st2, b_st2, aggA, NT);  // o_t
    fused_lin<false><<<glin, 256, 0, stream>>>(aggB, h_s, Wl_ts2, Wr_ts2, b_ts2, aggB, NS);  // o_s

    // link scores: o_s[ell_src] . o_t[ell_dst]
    dot_kernel<<<(EL + 3) / 4, 256, 0, stream>>>(aggB, aggA, ell, out, EL);
}

// Round 2
// 1179.615 us; speedup vs baseline: 1.4461x; 1.4461x over previous
//
#include <hip/hip_runtime.h>
#include <hip/hip_bf16.h>

#define H 64
#define NXCD 8

// ---------------------------------------------------------------- count (XCD-partitioned)
__global__ void count_kernel(const int* __restrict__ eidx, int* __restrict__ cnt_t,
                             int* __restrict__ cnt_s, int E, int NNt, int NNs) {
    int g = blockIdx.x & (NXCD - 1);
    int bg = blockIdx.x >> 3;
    int nbg = gridDim.x >> 3;
    int CSt = (NNt + NXCD - 1) >> 3;
    int CSs = (NNs + NXCD - 1) >> 3;
    int lot = g * CSt, hit = lot + CSt;
    int los = g * CSs, his = los + CSs;
    int stride = nbg * blockDim.x;
    for (int e = bg * blockDim.x + threadIdx.x; e < E; e += stride) {
        int s = eidx[e];
        int d = eidx[E + e];
        if (d >= lot && d < hit) atomicAdd(&cnt_t[d], 1);
        if (s >= los && s < his) atomicAdd(&cnt_s[s], 1);
    }
}

// ---------------------------------------------------------------- scan (3-phase)
__global__ void scan_local(const int* __restrict__ cnt, int* __restrict__ off,
                           int* __restrict__ partials, int n) {
    int arr = blockIdx.y;
    const int* c = cnt + (size_t)arr * n;
    int* o = off + (size_t)arr * n;
    int base = blockIdx.x * 1024;
    int tid = threadIdx.x;
    int v[4];
    int t = 0;
#pragma unroll
    for (int q = 0; q < 4; q++) {
        int i = base + tid * 4 + q;
        v[q] = (i < n) ? c[i] : 0;
        t += v[q];
    }
    __shared__ int s[256];
    s[tid] = t;
    __syncthreads();
    for (int ofs = 1; ofs < 256; ofs <<= 1) {
        int add = (tid >= ofs) ? s[tid - ofs] : 0;
        __syncthreads();
        s[tid] += add;
        __syncthreads();
    }
    int excl = s[tid] - t;
#pragma unroll
    for (int q = 0; q < 4; q++) {
        int i = base + tid * 4 + q;
        if (i < n) o[i] = excl;
        excl += v[q];
    }
    if (tid == 0) partials[arr * 128 + blockIdx.x] = s[255];
}

__global__ void scan_partials(int* __restrict__ partials, int nblk) {
    int t = threadIdx.x;
    if (t < 2) {
        int run = 0;
        for (int b = 0; b < nblk; b++) {
            int p = partials[t * 128 + b];
            partials[t * 128 + b] = run;
            run += p;
        }
    }
}

__global__ void scan_add(int* __restrict__ off, const int* __restrict__ partials, int n) {
    int arr = blockIdx.y;
    int* o = off + (size_t)arr * n;
    int add = partials[arr * 128 + blockIdx.x];
    int base = blockIdx.x * 1024;
    int tid = threadIdx.x;
#pragma unroll
    for (int q = 0; q < 4; q++) {
        int i = base + tid * 4 + q;
        if (i < n) o[i] += add;
    }
}

// ---------------------------------------------------------------- fill CSR (XCD-partitioned)
__global__ void fill_kernel(const int* __restrict__ eidx,
                            const int* __restrict__ off_t, const int* __restrict__ off_s,
                            int* __restrict__ cur_t, int* __restrict__ cur_s,
                            int* __restrict__ csr_t, int* __restrict__ csr_s,
                            int E, int NNt, int NNs) {
    int g = blockIdx.x & (NXCD - 1);
    int bg = blockIdx.x >> 3;
    int nbg = gridDim.x >> 3;
    int CSt = (NNt + NXCD - 1) >> 3;
    int CSs = (NNs + NXCD - 1) >> 3;
    int lot = g * CSt, hit = lot + CSt;
    int los = g * CSs, his = los + CSs;
    int stride = nbg * blockDim.x;
    for (int e = bg * blockDim.x + threadIdx.x; e < E; e += stride) {
        int s = eidx[e];
        int d = eidx[E + e];
        if (d >= lot && d < hit) {
            int p = atomicAdd(&cur_t[d], 1);
            csr_t[off_t[d] + p] = s;
        }
        if (s >= los && s < his) {
            int p = atomicAdd(&cur_s[s], 1);
            csr_s[off_s[s] + p] = d;
        }
    }
}

// ---------------------------------------------------------------- mean aggregation
// one wave per node; 16 lanes x float4 per row, 4 neighbor rows in flight
__global__ void agg_mean(const float* __restrict__ x, const int* __restrict__ csr,
                         const int* __restrict__ off, const int* __restrict__ cnt,
                         float* __restrict__ out, int n) {
    int wv = threadIdx.x >> 6, lane = threadIdx.x & 63;
    int q = lane >> 4, p = lane & 15;
    int node = blockIdx.x * 4 + wv;
    if (node >= n) return;
    int o = off[node], c = cnt[node];
    float4 acc = {0.f, 0.f, 0.f, 0.f};
    for (int k = q; k < c; k += 4) {
        int idx = csr[o + k];
        float4 v = *(const float4*)(x + (size_t)idx * H + p * 4);
        acc.x += v.x; acc.y += v.y; acc.z += v.z; acc.w += v.w;
    }
#pragma unroll
    for (int m = 16; m <= 32; m <<= 1) {
        acc.x += __shfl_xor(acc.x, m, 64);
        acc.y += __shfl_xor(acc.y, m, 64);
        acc.z += __shfl_xor(acc.z, m, 64);
        acc.w += __shfl_xor(acc.w, m, 64);
    }
    if (q == 0) {
        float inv = 1.f / fmaxf((float)c, 1.f);
        float4 r = {acc.x * inv, acc.y * inv, acc.z * inv, acc.w * inv};
        *(float4*)(out + (size_t)node * H + p * 4) = r;
    }
}

// ---------------------------------------------------------------- fused linear
template <bool RELU>
__global__ __launch_bounds__(256, 2) void fused_lin(const float* __restrict__ agg,
                                                    const float* __restrict__ xd,
                                                    const float* __restrict__ Wl,
                                                    const float* __restrict__ Wr,
                                                    const float* __restrict__ b,
                                                    float* __restrict__ out, int n) {
    int tid = threadIdx.x;
    int w = tid >> 6, j = tid & 63;
    float wl[H], wr[H];
#pragma unroll
    for (int k = 0; k < H; k++) {
        wl[k] = Wl[k * H + j];
        wr[k] = Wr[k * H + j];
    }
    float bj = b[j];
    int base = blockIdx.x * 64;
    for (int it = 0; it < 16; ++it) {
        int node = base + it * 4 + w;
        if (node < n) {
            const float4* av = (const float4*)(agg + (size_t)node * H);
            const float4* xv = (const float4*)(xd + (size_t)node * H);
            float acc = bj;
#pragma unroll
            for (int k4 = 0; k4 < 16; k4++) {
                float4 a = av[k4];
                float4 xx = xv[k4];
                acc += a.x * wl[4 * k4 + 0] + a.y * wl[4 * k4 + 1] +
                       a.z * wl[4 * k4 + 2] + a.w * wl[4 * k4 + 3];
                acc += xx.x * wr[4 * k4 + 0] + xx.y * wr[4 * k4 + 1] +
                       xx.z * wr[4 * k4 + 2] + xx.w * wr[4 * k4 + 3];
            }
            out[(size_t)node * H + j] = RELU ? fmaxf(acc, 0.f) : acc;
        }
    }
}

// ---------------------------------------------------------------- link scores
// 16 lanes per label edge, float4 loads, 4 edges per wave
__global__ void dot_kernel(const float* __restrict__ os, const float* __restrict__ ot,
                           const int* __restrict__ ell, float* __restrict__ out, int ne) {
    int wv = threadIdx.x >> 6, lane = threadIdx.x & 63;
    int q = lane >> 4, p = lane & 15;
    int l = (blockIdx.x * 4 + wv) * 4 + q;
    if (l >= ne) return;
    int s = ell[l];
    int d = ell[ne + l];
    float4 a = *(const float4*)(os + (size_t)s * H + p * 4);
    float4 b = *(const float4*)(ot + (size_t)d * H + p * 4);
    float pr = a.x * b.x + a.y * b.y + a.z * b.z + a.w * b.w;
#pragma unroll
    for (int m = 1; m <= 8; m <<= 1) pr += __shfl_xor(pr, m, 64);
    if (p == 0) out[l] = pr;
}

// ----------------------------------------------------------------
static inline size_t alignup(size_t x) { return (x + 255) & ~(size_t)255; }

extern "C" void kernel_launch(void* const* d_in, const int* in_sizes, int n_in,
                              void* d_out, int out_size, void* d_ws, size_t ws_size,
                              hipStream_t stream) {
    const float* src_emb = (const float*)d_in[0];
    const float* tgt_emb = (const float*)d_in[1];
    const float* Wl_st1 = (const float*)d_in[2];
    const float* Wr_st1 = (const float*)d_in[3];
    const float* b_st1 = (const float*)d_in[4];
    const float* Wl_ts1 = (const float*)d_in[5];
    const float* Wr_ts1 = (const float*)d_in[6];
    const float* b_ts1 = (const float*)d_in[7];
    const float* Wl_st2 = (const float*)d_in[8];
    const float* Wr_st2 = (const float*)d_in[9];
    const float* b_st2 = (const float*)d_in[10];
    const float* Wl_ts2 = (const float*)d_in[11];
    const float* Wr_ts2 = (const float*)d_in[12];
    const float* b_ts2 = (const float*)d_in[13];
    const int* eidx = (const int*)d_in[14];
    const int* ell = (const int*)d_in[15];

    const int NS = in_sizes[0] / H;
    const int NT = in_sizes[1] / H;
    const int E = in_sizes[14] / 2;
    const int EL = in_sizes[15] / 2;
    const int NN = NT;  // NS == NT here

    char* ws = (char*)d_ws;
    size_t o_cnt = 0;
    size_t o_cur = alignup(o_cnt + (size_t)2 * NN * 4);
    size_t o_off = alignup(o_cur + (size_t)2 * NN * 4);
    size_t o_par = alignup(o_off + (size_t)2 * NN * 4);
    size_t o_csrt = alignup(o_par + 1024);
    size_t o_csrs = alignup(o_csrt + (size_t)E * 4);
    size_t o_aggA = alignup(o_csrs + (size_t)E * 4);
    size_t o_aggB = alignup(o_aggA + (size_t)NN * H * 4);
    size_t o_ht = alignup(o_aggB + (size_t)NN * H * 4);
    size_t o_hs = alignup(o_ht + (size_t)NN * H * 4);

    int* cnt = (int*)(ws + o_cnt);
    int* cnt_t = cnt;
    int* cnt_s = cnt + NN;
    int* cur_t = (int*)(ws + o_cur);
    int* cur_s = cur_t + NN;
    int* off = (int*)(ws + o_off);
    int* off_t = off;
    int* off_s = off + NN;
    int* par = (int*)(ws + o_par);
    int* csr_t = (int*)(ws + o_csrt);
    int* csr_s = (int*)(ws + o_csrs);
    float* aggA = (float*)(ws + o_aggA);
    float* aggB = (float*)(ws + o_aggB);
    float* h_t = (float*)(ws + o_ht);
    float* h_s = (float*)(ws + o_hs);
    float* out = (float*)d_out;

    hipMemsetAsync(ws + o_cnt, 0, o_off - o_cnt, stream);

    count_kernel<<<2048, 256, 0, stream>>>(eidx, cnt_t, cnt_s, E, NT, NS);

    int nblk = (NN + 1023) / 1024;
    scan_local<<<dim3(nblk, 2), 256, 0, stream>>>(cnt, off, par, NN);
    scan_partials<<<1, 64, 0, stream>>>(par, nblk);
    scan_add<<<dim3(nblk, 2), 256, 0, stream>>>(off, par, NN);

    fill_kernel<<<2048, 256, 0, stream>>>(eidx, off_t, off_s, cur_t, cur_s,
                                          csr_t, csr_s, E, NT, NS);

    int gagg = (NN + 3) / 4;
    int glin = (NN + 63) / 64;

    // layer 1
    agg_mean<<<gagg, 256, 0, stream>>>(src_emb, csr_t, off_t, cnt_t, aggA, NT);
    agg_mean<<<gagg, 256, 0, stream>>>(tgt_emb, csr_s, off_s, cnt_s, aggB, NS);
    fused_lin<true><<<glin, 256, 0, stream>>>(aggA, tgt_emb, Wl_st1, Wr_st1, b_st1, h_t, NT);
    fused_lin<true><<<glin, 256, 0, stream>>>(aggB, src_emb, Wl_ts1, Wr_ts1, b_ts1, h_s, NS);

    // layer 2
    agg_mean<<<gagg, 256, 0, stream>>>(h_s, csr_t, off_t, cnt_t, aggA, NT);
    agg_mean<<<gagg, 256, 0, stream>>>(h_t, csr_s, off_s, cnt_s, aggB, NS);
    fused_lin<false><<<glin, 256, 0, stream>>>(aggA, h_t, Wl_st2, Wr_st2, b_st2, aggA, NT);
    fused_lin<false><<<glin, 256, 0, stream>>>(aggB, h_s, Wl_ts2, Wr_ts2, b_ts2, aggB, NS);

    dot_kernel<<<(EL + 15) / 16, 256, 0, stream>>>(aggB, aggA, ell, out, EL);
}